// Round 2
// baseline (84.779 us; speedup 1.0000x reference)
//
#include <hip/hip_runtime.h>

// counts[b,s] = #{t <= s : x[b,t] == x[b,s]}  (inclusive), B=4, S=4096.
// Single kernel, no atomics: block (qt, b) owns query tile qt (256 queries,
// one per thread). Thread loops chunks c = 0..qt staged in LDS (all lanes
// read the same LDS word per step -> broadcast, conflict-free), then writes
// its final count with one plain store (no zeroing pass needed).

#define SEQ 4096

__global__ __launch_bounds__(256)
void count_kernel(const int* __restrict__ x, float* __restrict__ out) {
    const int qt  = blockIdx.x;   // query tile 0..15
    const int b   = blockIdx.y;   // batch row
    const int tid = threadIdx.x;
    const int* __restrict__ row = x + b * SEQ;
    const int s = (qt << 8) + tid;
    const int q = row[s];

    __shared__ int tile[256];
    int cnt = 0;

    // full chunks: every t in chunk is <= s
    for (int c = 0; c < qt; ++c) {
        tile[tid] = row[(c << 8) + tid];
        __syncthreads();
        #pragma unroll 16
        for (int k = 0; k < 256; k += 4) {
            int4 a = *reinterpret_cast<const int4*>(&tile[k]);
            cnt += (q == a.x) + (q == a.y) + (q == a.z) + (q == a.w);
        }
        __syncthreads();
    }

    // diagonal chunk (c == qt): local index k qualifies iff k <= tid (incl. self)
    tile[tid] = q;
    __syncthreads();
    #pragma unroll 16
    for (int k = 0; k < 256; k += 4) {
        int4 a = *reinterpret_cast<const int4*>(&tile[k]);
        cnt += (int)((k + 0 <= tid) & (q == a.x))
             + (int)((k + 1 <= tid) & (q == a.y))
             + (int)((k + 2 <= tid) & (q == a.z))
             + (int)((k + 3 <= tid) & (q == a.w));
    }

    out[b * SEQ + s] = (float)cnt;
}

extern "C" void kernel_launch(void* const* d_in, const int* in_sizes, int n_in,
                              void* d_out, int out_size, void* d_ws, size_t ws_size,
                              hipStream_t stream) {
    const int* x = (const int*)d_in[0];
    float* out = (float*)d_out;
    const int B = in_sizes[0] / SEQ;   // 4

    count_kernel<<<dim3(SEQ / 256, B), 256, 0, stream>>>(x, out);
}

// Round 4
// 62.899 us; speedup vs baseline: 1.3479x; 1.3479x over previous
//
#include <hip/hip_runtime.h>

// counts[b,s] = #{t <= s : x[b,t] == x[b,s]}  (inclusive), B=4, S=4096.
// One kernel, no atomics, balanced: grid (qt 0..63, b 0..3) = 256 blocks
// (one per CU, all co-resident). Block owns 64 queries; 256 threads =
// 4 t-slices x 64 queries. Whole prefix [0, (qt+1)*64) staged in LDS once;
// each slice scans a contiguous QUARTER of the full region (4*qt int4s --
// R3 bug was qt int4s) via broadcast ds_read_b128; 4-way LDS reduction.

#define SEQ 4096
#define QT  64    // queries per block

__global__ __launch_bounds__(256)
void count_kernel(const int* __restrict__ x, float* __restrict__ out) {
    const int qt  = blockIdx.x;          // query tile 0..63
    const int b   = blockIdx.y;          // batch row
    const int tid = threadIdx.x;
    const int q   = tid & 63;            // query lane
    const int g   = tid >> 6;            // t-slice / wave id 0..3
    const int* __restrict__ row = x + b * SEQ;

    __shared__ int prefix[SEQ];          // 16 KB max
    __shared__ int partial[4][QT];

    const int end_i4 = (qt + 1) * (QT / 4);   // prefix length in int4s
    for (int j = tid; j < end_i4; j += 256)
        reinterpret_cast<int4*>(prefix)[j] =
            reinterpret_cast<const int4*>(row)[j];
    __syncthreads();

    const int s    = (qt << 6) + q;
    const int qval = prefix[s];

    // full region: t in [0, qt*64) = qt*16 int4s; slice g scans
    // int4 indices [g*4*qt, (g+1)*4*qt)
    int cnt = 0;
    const int lo = g * (qt << 2);
    const int hi = lo + (qt << 2);
    #pragma unroll 4
    for (int j = lo; j < hi; ++j) {
        int4 a = reinterpret_cast<const int4*>(prefix)[j];
        cnt += (qval == a.x) + (qval == a.y) + (qval == a.z) + (qval == a.w);
    }

    // diagonal: t = qt*64 + k, k in [g*16, (g+1)*16), qualifies iff k <= q
    const int dbase = qt * (QT / 4);      // int4 index of diagonal start
    #pragma unroll 4
    for (int jj = 0; jj < 4; ++jj) {
        const int k = (g << 4) + (jj << 2);   // local element index
        int4 a = reinterpret_cast<const int4*>(prefix)[dbase + (k >> 2)];
        cnt += (int)((k + 0 <= q) & (qval == a.x))
             + (int)((k + 1 <= q) & (qval == a.y))
             + (int)((k + 2 <= q) & (qval == a.z))
             + (int)((k + 3 <= q) & (qval == a.w));
    }

    partial[g][q] = cnt;
    __syncthreads();

    if (tid < QT) {
        int tot = partial[0][tid] + partial[1][tid]
                + partial[2][tid] + partial[3][tid];
        out[b * SEQ + (qt << 6) + tid] = (float)tot;
    }
}

extern "C" void kernel_launch(void* const* d_in, const int* in_sizes, int n_in,
                              void* d_out, int out_size, void* d_ws, size_t ws_size,
                              hipStream_t stream) {
    const int* x = (const int*)d_in[0];
    float* out = (float*)d_out;
    const int B = in_sizes[0] / SEQ;   // 4

    count_kernel<<<dim3(SEQ / QT, B), 256, 0, stream>>>(x, out);
}